// Round 13
// baseline (184.981 us; speedup 1.0000x reference)
//
#include <hip/hip_runtime.h>
#include <cstdint>

constexpr int NV = 32000;   // vocab / N
constexpr int NE = 256;     // embed dim
constexpr int NH = 512;     // hidden / K
constexpr int NB = 8;       // batch
constexpr int NS = 16;      // seq len
constexpr int NT = 20;      // time steps
constexpr float TH1 = 0.8f;
constexpr float TH2 = 1.0f;

typedef _Float16 f16x8 __attribute__((ext_vector_type(8)));
typedef float f32x4 __attribute__((ext_vector_type(4)));

__device__ inline float clip01(float v) { return fminf(fmaxf(v, 0.f), 1.f); }

// LDS-write drain + barrier (vmcnt left in flight: A prefetch crosses barriers)
__device__ inline void bar_lds() {
  asm volatile("s_waitcnt lgkmcnt(0)" ::: "memory");
  __builtin_amdgcn_s_barrier();
  __builtin_amdgcn_sched_barrier(0);
}

// ---------------- K1: cur1[b][s][h] = embed[x[b,s],:] . W1[h,:] + b1[h] ----------------
__global__ void k_cur1(const int* __restrict__ x, const float* __restrict__ embed,
                       const float* __restrict__ W1, const float* __restrict__ b1,
                       float* __restrict__ cur1) {
  __shared__ float e[NE];
  int bs = blockIdx.x;
  int row = x[bs];
  e[threadIdx.x] = embed[(size_t)row * NE + threadIdx.x];
  __syncthreads();
  for (int hh = 0; hh < 2; ++hh) {
    int h = threadIdx.x + hh * 256;
    const float* w = W1 + (size_t)h * NE;
    float acc = 0.f;
#pragma unroll 8
    for (int k = 0; k < NE; ++k) acc = fmaf(e[k], w[k], acc);
    cur1[(size_t)bs * NH + h] = acc + b1[h];
  }
}

// ---------------- K2: leaky recurrence -> frag-major spike matrix A2F ----------------
// A2F layout (f16 elems): [mt 40][kfi 16][rb 4][lane 64][e 8]; frag = 512 f16 = 1KB.
// Element (gs, b, h):  mt=gs>>3, kfi=h>>5, row=(gs&7)*8+b, rb=row>>4, lr=row&15,
// lane=((h&31)>>3)*16+lr, e=h&7.   (MFMA A-operand: row=lane&15, k=kfi*32+(lane>>4)*8+e)
__global__ void k_spk1(const float* __restrict__ cur1, const float* __restrict__ pbeta1,
                       _Float16* __restrict__ A2F, float* __restrict__ mem1_out) {
  int g = blockIdx.x * blockDim.x + threadIdx.x;   // 4096 = NB*NH
  int b = g >> 9, h = g & 511;
  float bc = clip01(pbeta1[0]);
  float mem = 0.f;
  const _Float16 one  = (_Float16)1.0f;
  const _Float16 zero = (_Float16)0.0f;
  const int kfi = h >> 5;
  const int lhi = (h & 31) >> 3;
  const int e   = h & 7;
  for (int s = 0; s < NS; ++s) {
    float c = cur1[((size_t)b * NS + s) * NH + h];
    for (int t = 0; t < NT; ++t) {
      float rst = (mem > TH1) ? TH1 : 0.f;
      mem = __fsub_rn(__fadd_rn(__fmul_rn(bc, mem), c), rst);    // np order
      bool spk = mem > TH1;
      int gs = s * NT + t;
      int row = (gs & 7) * 8 + b;
      int lane = lhi * 16 + (row & 15);
      size_t addr = ((((size_t)(gs >> 3) * 16 + kfi) * 4 + (row >> 4)) * 64 + lane) * 8 + e;
      A2F[addr] = spk ? one : zero;
    }
  }
  mem1_out[g] = mem;
}

// ---------------- Fused: low-amplification A-from-L2 GEMM (n=64 strip) + recurrence -------
// Grid 500 (2 generations/CU).  Block = 1024 thr = 16 waves: (kq 2) x (wm 4) x (wn 2).
// Wave tile: m16 x n32 x K256.  B = 2 n-frags x 8 k-frags = 16 f16x8 = 64 regs.
// A frags from L2-resident A2F, amp-2 only; ring-of-4 regs, 2-kf lookahead (compiler vmcnt).
// Cl = [2 buf][2 kq][64 x 66] f32 (66 KB) -> ONE barrier/mt; recur(mt-1) overlaps GEMM(mt).
__global__ __launch_bounds__(1024, 4) void k_fused(
    const _Float16* __restrict__ A2F,  // frag-major spike matrix (2.62 MB, L2-resident)
    const float* __restrict__ W2,      // [32000][512] fp32
    const float* __restrict__ b2,
    const float* __restrict__ pa2, const float* __restrict__ pb2,
    float* __restrict__ out) {
  __shared__ float Cl[2][2][64 * 66];  // 67.6 KB

  const int tid  = threadIdx.x;
  const int lane = tid & 63;
  const int wid  = tid >> 6;           // 0..15
  const int kq   = wid >> 3;           // K half: K in [kq*256, +256)
  const int wm   = (wid >> 1) & 3;     // m quarter: rows wm*16..+15
  const int wn   = wid & 1;            // n half: cols wn*32..+31
  const int n0   = blockIdx.x * 64;

  const int lr  = lane & 15;
  const int lk8 = (lane >> 4) * 8;
  const int cr  = (lane >> 4) * 4, cc = lane & 15;

  // ---- B prologue: 2 n-frags x 8 k-frags, fp16 ----
  f16x8 bfr[2][8];
#pragma unroll
  for (int nf = 0; nf < 2; ++nf) {
    const int n = n0 + wn * 32 + nf * 16 + lr;
    const float* wp = W2 + (size_t)n * NH + kq * 256;
#pragma unroll
    for (int kf = 0; kf < 8; ++kf) {
      const float4 wa = *(const float4*)(wp + kf * 32 + lk8);
      const float4 wb = *(const float4*)(wp + kf * 32 + lk8 + 4);
      f16x8 v;
      v[0] = (_Float16)wa.x; v[1] = (_Float16)wa.y;
      v[2] = (_Float16)wa.z; v[3] = (_Float16)wa.w;
      v[4] = (_Float16)wb.x; v[5] = (_Float16)wb.y;
      v[6] = (_Float16)wb.z; v[7] = (_Float16)wb.w;
      bfr[nf][kf] = v;
    }
  }

  const float a2  = clip01(pa2[0]);
  const float bcl = clip01(pb2[0]);
  const int vv = tid & 63;             // recurrence (tid<512): owned column
  const int bb = (tid >> 6) & 7;       // recurrence: owned batch
  const float b2v = b2[n0 + vv];
  float syn = 0.f, mem = 0.f;
  unsigned spkmask = 0;
  f32x4 acc[2] = {};

  // wave-constant A base: frag(MT,KF) at pAW + MT*32768 + KF*2048
  const _Float16* pAW = A2F + (size_t)(kq * 8) * 2048 + wm * 512 + lane * 8;

  f16x8 a0_, a1_, a2_, a3_;            // ring of 4, slot = kf & 3

#define LD(SLOT, MT, KF) SLOT = *(const f16x8*)(pAW + (size_t)(MT) * 32768 + (KF) * 2048);
#define FM(SLOT, KF)                                                               \
  {                                                                                \
    acc[0] = __builtin_amdgcn_mfma_f32_16x16x32_f16(SLOT, bfr[0][KF], acc[0], 0, 0, 0); \
    acc[1] = __builtin_amdgcn_mfma_f32_16x16x32_f16(SLOT, bfr[1][KF], acc[1], 0, 0, 0); \
  }

  // recurrence for tile mtq (reads Cl[mtq&1]; 16 indep ds_reads + short VALU chain)
  auto recur = [&](int mtq) {
    if (tid < 512) {
      const float* C0 = Cl[mtq & 1][0];
      const float* C1 = Cl[mtq & 1][1];
#pragma unroll
      for (int st = 0; st < 8; ++st) {
        const int gs = mtq * 8 + st;
        const int idx = (st * 8 + bb) * 66 + vv;
        float cur2 = __fadd_rn(__fadd_rn(C0[idx], C1[idx]), b2v);
        float rst = (mem > TH2) ? 1.f : 0.f;           // reset from OLD mem2
        syn = __fadd_rn(__fmul_rn(a2, syn), cur2);
        mem = __fsub_rn(__fadd_rn(__fmul_rn(bcl, mem), syn), rst);
        if (gs % 20 == 19)                             // last inner step of seq pos
          spkmask |= (mem > TH2 ? 1u : 0u) << (gs / 20);
      }
    }
  };

  LD(a0_, 0, 0); LD(a1_, 0, 1);

  for (int mt = 0; mt < 40; ++mt) {
    LD(a2_, mt, 2);
    if (mt > 0) recur(mt - 1);         // overlaps the MFMA cluster below
    __builtin_amdgcn_s_setprio(1);
    FM(a0_, 0)
    LD(a3_, mt, 3)  FM(a1_, 1)
    LD(a0_, mt, 4)  FM(a2_, 2)
    LD(a1_, mt, 5)  FM(a3_, 3)
    LD(a2_, mt, 6)  FM(a0_, 4)
    LD(a3_, mt, 7)  FM(a1_, 5)
    if (mt < 39) { LD(a0_, mt + 1, 0) }
    FM(a2_, 6)
    if (mt < 39) { LD(a1_, mt + 1, 1) }
    FM(a3_, 7)
    __builtin_amdgcn_s_setprio(0);

    // ---- epilogue: wave writes its kq plane, rows wm*16..+15, cols wn*32..+31 ----
    float* Cw = Cl[mt & 1][kq];
#pragma unroll
    for (int nf = 0; nf < 2; ++nf) {
#pragma unroll
      for (int j = 0; j < 4; ++j)
        Cw[(wm * 16 + cr + j) * 66 + wn * 32 + nf * 16 + cc] = acc[nf][j];
      acc[nf] = (f32x4){0.f, 0.f, 0.f, 0.f};
    }
    bar_lds();                         // ONE rendezvous per mt
  }
  recur(39);
#undef LD
#undef FM

  // ---- outputs ----
  if (tid < 512) {
#pragma unroll
    for (int s = 0; s < NS; ++s)
      out[((size_t)bb * NS + s) * NV + n0 + vv] = (spkmask >> s) & 1 ? 1.f : 0.f;
    out[(size_t)4100096 + (size_t)bb * NV + n0 + vv] = syn;   // syn2
    out[(size_t)4356096 + (size_t)bb * NV + n0 + vv] = mem;   // mem2
  }
}

extern "C" void kernel_launch(void* const* d_in, const int* in_sizes, int n_in,
                              void* d_out, int out_size, void* d_ws, size_t ws_size,
                              hipStream_t stream) {
  const int*   x     = (const int*)d_in[0];
  const float* embed = (const float*)d_in[1];
  const float* W1    = (const float*)d_in[2];
  const float* b1    = (const float*)d_in[3];
  const float* W2    = (const float*)d_in[4];
  const float* b2    = (const float*)d_in[5];
  const float* pb1   = (const float*)d_in[6];
  const float* pa2   = (const float*)d_in[7];
  const float* pb2   = (const float*)d_in[8];
  float* out = (float*)d_out;

  char* ws = (char*)d_ws;
  float* cur1 = (float*)ws;                            // 262144 B
  _Float16* A2F = (_Float16*)(ws + 262144);            // 40*16*4*512 f16 = 2.62 MB

  hipLaunchKernelGGL(k_cur1, dim3(NB * NS), dim3(256), 0, stream, x, embed, W1, b1, cur1);
  hipLaunchKernelGGL(k_spk1, dim3(16), dim3(256), 0, stream, cur1, pb1, A2F, out + 4096000);
  hipLaunchKernelGGL(k_fused, dim3(NV / 64), dim3(1024), 0, stream,
                     A2F, W2, b2, pa2, pb2, out);
}

// Round 14
// 160.213 us; speedup vs baseline: 1.1546x; 1.1546x over previous
//
#include <hip/hip_runtime.h>
#include <cstdint>

constexpr int NV = 32000;   // vocab / N
constexpr int NE = 256;     // embed dim
constexpr int NH = 512;     // hidden / K
constexpr int NB = 8;       // batch
constexpr int NS = 16;      // seq len
constexpr int NT = 20;      // time steps
constexpr float TH1 = 0.8f;
constexpr float TH2 = 1.0f;

typedef _Float16 f16x8 __attribute__((ext_vector_type(8)));
typedef float f32x4 __attribute__((ext_vector_type(4)));

__device__ inline float clip01(float v) { return fminf(fmaxf(v, 0.f), 1.f); }

// LDS-write drain + barrier (vmcnt left in flight: A prefetch crosses barriers)
__device__ inline void bar_lds() {
  asm volatile("s_waitcnt lgkmcnt(0)" ::: "memory");
  __builtin_amdgcn_s_barrier();
  __builtin_amdgcn_sched_barrier(0);
}

// ---------------- K1: cur1[b][s][h] = embed[x[b,s],:] . W1[h,:] + b1[h] ----------------
__global__ void k_cur1(const int* __restrict__ x, const float* __restrict__ embed,
                       const float* __restrict__ W1, const float* __restrict__ b1,
                       float* __restrict__ cur1) {
  __shared__ float e[NE];
  int bs = blockIdx.x;
  int row = x[bs];
  e[threadIdx.x] = embed[(size_t)row * NE + threadIdx.x];
  __syncthreads();
  for (int hh = 0; hh < 2; ++hh) {
    int h = threadIdx.x + hh * 256;
    const float* w = W1 + (size_t)h * NE;
    float acc = 0.f;
#pragma unroll 8
    for (int k = 0; k < NE; ++k) acc = fmaf(e[k], w[k], acc);
    cur1[(size_t)bs * NH + h] = acc + b1[h];
  }
}

// ---------------- K2: leaky recurrence -> frag-major spike matrix A2F ----------------
// A2F layout (f16 elems): [mt 40][kfi 16][rb 4][lane 64][e 8]; frag = 512 f16 = 1KB.
// Element (gs, b, h):  mt=gs>>3, kfi=h>>5, row=(gs&7)*8+b, rb=row>>4, lr=row&15,
// lane=((h&31)>>3)*16+lr, e=h&7.   (MFMA A-operand: row=lane&15, k=kfi*32+(lane>>4)*8+e)
__global__ void k_spk1(const float* __restrict__ cur1, const float* __restrict__ pbeta1,
                       _Float16* __restrict__ A2F, float* __restrict__ mem1_out) {
  int g = blockIdx.x * blockDim.x + threadIdx.x;   // 4096 = NB*NH
  int b = g >> 9, h = g & 511;
  float bc = clip01(pbeta1[0]);
  float mem = 0.f;
  const _Float16 one  = (_Float16)1.0f;
  const _Float16 zero = (_Float16)0.0f;
  const int kfi = h >> 5;
  const int lhi = (h & 31) >> 3;
  const int e   = h & 7;
  for (int s = 0; s < NS; ++s) {
    float c = cur1[((size_t)b * NS + s) * NH + h];
    for (int t = 0; t < NT; ++t) {
      float rst = (mem > TH1) ? TH1 : 0.f;
      mem = __fsub_rn(__fadd_rn(__fmul_rn(bc, mem), c), rst);    // np order
      bool spk = mem > TH1;
      int gs = s * NT + t;
      int row = (gs & 7) * 8 + b;
      int lane = lhi * 16 + (row & 15);
      size_t addr = ((((size_t)(gs >> 3) * 16 + kfi) * 4 + (row >> 4)) * 64 + lane) * 8 + e;
      A2F[addr] = spk ? one : zero;
    }
  }
  mem1_out[g] = mem;
}

// ---------------- Fused: fat-wave A-from-L2 GEMM (n=128 strip) + recurrence ---------------
// Grid 250 = 1 block/CU.  Block = 512 thr = 8 waves (2/SIMD): (kq 2) x (wm 2) x (wn 2).
// Wave tile: m32 x n64 x K256 -> B = 4nf x 8kf = 32 f16x8 = 128 VGPR; n-per-A-fetch = 64
// (halves device A-traffic to 1.31 GB).  A ring-8 regs, 4-kf lookahead, compiler vmcnt.
// Cl = [2 buf][2 kq][64 x 132] f32 -> ONE barrier/mt; recur(mt-1, 2 cols/thr) overlaps GEMM.
__global__ __launch_bounds__(512, 2) void k_fused(
    const _Float16* __restrict__ A2F,  // frag-major spike matrix (2.62 MB, L2-resident)
    const float* __restrict__ W2,      // [32000][512] fp32
    const float* __restrict__ b2,
    const float* __restrict__ pa2, const float* __restrict__ pb2,
    float* __restrict__ out) {
  __shared__ float Cl[2][2][64 * 132];  // 132 KB

  const int tid  = threadIdx.x;
  const int lane = tid & 63;
  const int wid  = tid >> 6;           // 0..7
  const int kq   = wid >> 2;           // K half: [kq*256, +256)
  const int wm   = (wid >> 1) & 1;     // m half: rows wm*32..+31
  const int wn   = wid & 1;            // n half: cols wn*64..+63
  const int n0   = blockIdx.x * 128;

  const int lr  = lane & 15;
  const int lk8 = (lane >> 4) * 8;
  const int cr  = (lane >> 4) * 4, cc = lane & 15;

  // ---- B prologue: 4 n-frags x 8 k-frags, fp16 (128 VGPR) ----
  f16x8 bfr[4][8];
#pragma unroll
  for (int nf = 0; nf < 4; ++nf) {
    const int n = n0 + wn * 64 + nf * 16 + lr;
    const float* wp = W2 + (size_t)n * NH + kq * 256 + lk8;
#pragma unroll
    for (int kf = 0; kf < 8; ++kf) {
      const float4 wa = *(const float4*)(wp + kf * 32);
      const float4 wb = *(const float4*)(wp + kf * 32 + 4);
      f16x8 v;
      v[0] = (_Float16)wa.x; v[1] = (_Float16)wa.y;
      v[2] = (_Float16)wa.z; v[3] = (_Float16)wa.w;
      v[4] = (_Float16)wb.x; v[5] = (_Float16)wb.y;
      v[6] = (_Float16)wb.z; v[7] = (_Float16)wb.w;
      bfr[nf][kf] = v;
    }
  }

  const float a2  = clip01(pa2[0]);
  const float bcl = clip01(pb2[0]);
  const int vv = lane;                 // recurrence: owns cols vv, vv+64; batch bb = wid
  const int bb = wid;
  float b2v[2] = {b2[n0 + vv], b2[n0 + 64 + vv]};
  float syn[2] = {0.f, 0.f};
  float mem[2] = {0.f, 0.f};
  unsigned spkmask = 0;                // bits 0..15: col vv; bits 16..31: col vv+64
  f32x4 acc[4][2] = {};

  // wave-constant A base: frag(MT,KF,mb) at pAW + MT*32768 + KF*2048 + mb*512
  const _Float16* pAW = A2F + (size_t)kq * 16384 + wm * 1024 + lane * 8;

  f16x8 r0, r1, r2, r3, r4, r5, r6, r7;  // ring of 8 (4-kf lookahead)

#define LDP(R0, R1, MT, KF)                                                    \
  {                                                                            \
    const _Float16* fb = pAW + (size_t)(MT) * 32768 + (KF) * 2048;             \
    R0 = *(const f16x8*)(fb);                                                  \
    R1 = *(const f16x8*)(fb + 512);                                            \
  }
#define FMP(R0, R1, KF)                                                        \
  {                                                                            \
    acc[0][0] = __builtin_amdgcn_mfma_f32_16x16x32_f16(R0, bfr[0][KF], acc[0][0], 0, 0, 0); \
    acc[0][1] = __builtin_amdgcn_mfma_f32_16x16x32_f16(R1, bfr[0][KF], acc[0][1], 0, 0, 0); \
    acc[1][0] = __builtin_amdgcn_mfma_f32_16x16x32_f16(R0, bfr[1][KF], acc[1][0], 0, 0, 0); \
    acc[1][1] = __builtin_amdgcn_mfma_f32_16x16x32_f16(R1, bfr[1][KF], acc[1][1], 0, 0, 0); \
    acc[2][0] = __builtin_amdgcn_mfma_f32_16x16x32_f16(R0, bfr[2][KF], acc[2][0], 0, 0, 0); \
    acc[2][1] = __builtin_amdgcn_mfma_f32_16x16x32_f16(R1, bfr[2][KF], acc[2][1], 0, 0, 0); \
    acc[3][0] = __builtin_amdgcn_mfma_f32_16x16x32_f16(R0, bfr[3][KF], acc[3][0], 0, 0, 0); \
    acc[3][1] = __builtin_amdgcn_mfma_f32_16x16x32_f16(R1, bfr[3][KF], acc[3][1], 0, 0, 0); \
  }

  // recurrence for tile mtq: 2 columns per thread, reads both kq planes of Cl[mtq&1]
  auto recur = [&](int mtq) {
    const float* C0 = Cl[mtq & 1][0];
    const float* C1 = Cl[mtq & 1][1];
#pragma unroll
    for (int st = 0; st < 8; ++st) {
      const int gs = mtq * 8 + st;
      const int base = (st * 8 + bb) * 132 + vv;
#pragma unroll
      for (int p = 0; p < 2; ++p) {
        const int idx = base + p * 64;
        float cur2 = __fadd_rn(__fadd_rn(C0[idx], C1[idx]), b2v[p]);
        float rst = (mem[p] > TH2) ? 1.f : 0.f;        // reset from OLD mem2
        syn[p] = __fadd_rn(__fmul_rn(a2, syn[p]), cur2);
        mem[p] = __fsub_rn(__fadd_rn(__fmul_rn(bcl, mem[p]), syn[p]), rst);
      }
      if (gs % 20 == 19) {                             // last inner step of seq pos
        spkmask |= (mem[0] > TH2 ? 1u : 0u) << (gs / 20);
        spkmask |= (mem[1] > TH2 ? 1u : 0u) << (16 + gs / 20);
      }
    }
  };

  // prologue: first half of mt 0
  LDP(r0, r1, 0, 0) LDP(r2, r3, 0, 1) LDP(r4, r5, 0, 2) LDP(r6, r7, 0, 3)

  for (int mt = 0; mt < 40; ++mt) {
    if (mt > 0) recur(mt - 1);         // overlaps the MFMA cluster below
    __builtin_amdgcn_s_setprio(1);
    FMP(r0, r1, 0)  LDP(r0, r1, mt, 4)
    FMP(r2, r3, 1)  LDP(r2, r3, mt, 5)
    FMP(r4, r5, 2)  LDP(r4, r5, mt, 6)
    FMP(r6, r7, 3)  LDP(r6, r7, mt, 7)
    FMP(r0, r1, 4)  if (mt < 39) { LDP(r0, r1, mt + 1, 0) }
    FMP(r2, r3, 5)  if (mt < 39) { LDP(r2, r3, mt + 1, 1) }
    FMP(r4, r5, 6)  if (mt < 39) { LDP(r4, r5, mt + 1, 2) }
    FMP(r6, r7, 7)  if (mt < 39) { LDP(r6, r7, mt + 1, 3) }
    __builtin_amdgcn_s_setprio(0);

    // ---- epilogue: wave writes its kq plane, rows wm*32..+31, cols wn*64..+63 ----
    float* Cw = &Cl[mt & 1][kq][0];
#pragma unroll
    for (int nf = 0; nf < 4; ++nf) {
#pragma unroll
      for (int mb = 0; mb < 2; ++mb) {
#pragma unroll
        for (int j = 0; j < 4; ++j)
          Cw[(wm * 32 + mb * 16 + cr + j) * 132 + wn * 64 + nf * 16 + cc] = acc[nf][mb][j];
        acc[nf][mb] = (f32x4){0.f, 0.f, 0.f, 0.f};
      }
    }
    bar_lds();                         // ONE rendezvous per mt
  }
  recur(39);
#undef LDP
#undef FMP

  // ---- outputs ----
#pragma unroll
  for (int s = 0; s < NS; ++s) {
    out[((size_t)bb * NS + s) * NV + n0 + vv]      = (spkmask >> s) & 1 ? 1.f : 0.f;
    out[((size_t)bb * NS + s) * NV + n0 + 64 + vv] = (spkmask >> (16 + s)) & 1 ? 1.f : 0.f;
  }
  out[(size_t)4100096 + (size_t)bb * NV + n0 + vv]      = syn[0];   // syn2
  out[(size_t)4100096 + (size_t)bb * NV + n0 + 64 + vv] = syn[1];
  out[(size_t)4356096 + (size_t)bb * NV + n0 + vv]      = mem[0];   // mem2
  out[(size_t)4356096 + (size_t)bb * NV + n0 + 64 + vv] = mem[1];
}

extern "C" void kernel_launch(void* const* d_in, const int* in_sizes, int n_in,
                              void* d_out, int out_size, void* d_ws, size_t ws_size,
                              hipStream_t stream) {
  const int*   x     = (const int*)d_in[0];
  const float* embed = (const float*)d_in[1];
  const float* W1    = (const float*)d_in[2];
  const float* b1    = (const float*)d_in[3];
  const float* W2    = (const float*)d_in[4];
  const float* b2    = (const float*)d_in[5];
  const float* pb1   = (const float*)d_in[6];
  const float* pa2   = (const float*)d_in[7];
  const float* pb2   = (const float*)d_in[8];
  float* out = (float*)d_out;

  char* ws = (char*)d_ws;
  float* cur1 = (float*)ws;                            // 262144 B
  _Float16* A2F = (_Float16*)(ws + 262144);            // 40*16*4*512 f16 = 2.62 MB

  hipLaunchKernelGGL(k_cur1, dim3(NB * NS), dim3(256), 0, stream, x, embed, W1, b1, cur1);
  hipLaunchKernelGGL(k_spk1, dim3(16), dim3(256), 0, stream, cur1, pb1, A2F, out + 4096000);
  hipLaunchKernelGGL(k_fused, dim3(NV / 128), dim3(512), 0, stream,
                     A2F, W2, b2, pa2, pb2, out);
}